// Round 9
// baseline (2599.735 us; speedup 1.0000x reference)
//
#include <hip/hip_runtime.h>

// ---------------------------------------------------------------------------
// HeteroGNN forward — DIAGNOSTIC build v2.
// Round-8 telemetry isolated first corruption to the conv1-bp phase, whose
// only new kernel was fused_bgemm. This build removes fused_bgemm entirely
// (proj into hbuf + IN-PLACE hgemm, row-private so safe) and splits the
// conv1-bp phase into four diag slots. Clean -> real result.
// Sentinels: 500 = ws too small, 1000 = bad input map, 100+10k = diag slot k.
// ---------------------------------------------------------------------------

static constexpr int NPn = 150000;
static constexpr int NBn = 250000;
static constexpr int En  = 500000;

__device__ __forceinline__ float lrelu(float x, float s) { return x >= 0.0f ? x : s * x; }

struct WP { const void* p[44]; };

// bad if NaN, Inf, or |v| > 1e30
__global__ void scan_kernel(const float* __restrict__ buf, size_t n,
                            unsigned* __restrict__ diag, int slot) {
  __shared__ int sbad;
  if (threadIdx.x == 0) sbad = 0;
  __syncthreads();
  size_t stride = (size_t)gridDim.x * blockDim.x;
  int bad = 0;
  for (size_t i = (size_t)blockIdx.x * blockDim.x + threadIdx.x; i < n; i += stride) {
    float v = buf[i];
    if (!(fabsf(v) <= 1e30f)) { bad = 1; break; }
  }
  if (bad) sbad = 1;
  __syncthreads();
  if (threadIdx.x == 0 && sbad) atomicOr(&diag[slot], 1u);
}

__global__ void scan_weights_kernel(WP wp, unsigned* __restrict__ diag, int slot) {
  const int sz[44] = {2048,64,2048,64,1024,64,1024,64,1024,64,
                      4096,4096,64,64,64,64, 4096,4096,64,64,64,64,
                      4096,4096,4096,64,64,64,64, 4096,4096,64,64,64,64,
                      4096,4096,4096,64,64,64,64, 64,1};
  __shared__ int sbad;
  if (threadIdx.x == 0) sbad = 0;
  __syncthreads();
  int bad = 0;
  for (int seg = blockIdx.x; seg < 44; seg += gridDim.x) {
    const float* b = (const float*)wp.p[seg];
    for (int i = threadIdx.x; i < sz[seg]; i += blockDim.x) {
      float v = b[i];
      if (!(fabsf(v) <= 1e30f)) { bad = 1; }
    }
  }
  if (bad) sbad = 1;
  __syncthreads();
  if (threadIdx.x == 0 && sbad) atomicOr(&diag[slot], 1u);
}

__global__ void encode_kernel(const unsigned* __restrict__ diag,
                              const float* __restrict__ real,
                              float* __restrict__ out, int N) {
  int k = -1;
  for (int s = 0; s < 24; ++s)
    if (diag[s]) { k = s; break; }
  int i = blockIdx.x * blockDim.x + threadIdx.x;
  if (i >= N) return;
  out[i] = (k >= 0) ? (100.0f + 10.0f * (float)k) : real[i];
}

__global__ void fill_kernel(float* out, float val, int n) {
  int i = blockIdx.x * blockDim.x + threadIdx.x;
  if (i < n) out[i] = val;
}

// Y[N,64] = lrelu(X[N,32] @ W[32,64] + b, 0.01)
__global__ void proj_kernel(const float* __restrict__ X, const float* __restrict__ W,
                            const float* __restrict__ b, float* __restrict__ Y, int N) {
  __shared__ __align__(16) float Ws[32 * 64];
  __shared__ float bs[64];
  for (int i = threadIdx.x; i < 32 * 64; i += blockDim.x) Ws[i] = W[i];
  if (threadIdx.x < 64) bs[threadIdx.x] = b[threadIdx.x];
  __syncthreads();
  int row = blockIdx.x * blockDim.x + threadIdx.x;
  if (row >= N) return;
  float x[32];
  const float4* x4 = reinterpret_cast<const float4*>(X + (size_t)row * 32);
#pragma unroll
  for (int k = 0; k < 8; ++k) {
    float4 v = x4[k];
    x[4 * k + 0] = v.x; x[4 * k + 1] = v.y; x[4 * k + 2] = v.z; x[4 * k + 3] = v.w;
  }
  float4* y4 = reinterpret_cast<float4*>(Y + (size_t)row * 64);
#pragma unroll
  for (int cg = 0; cg < 4; ++cg) {
    float acc[16];
#pragma unroll
    for (int c = 0; c < 16; ++c) acc[c] = bs[cg * 16 + c];
#pragma unroll
    for (int k = 0; k < 32; ++k) {
      float xv = x[k];
      const float4* w4 = reinterpret_cast<const float4*>(&Ws[k * 64 + cg * 16]);
#pragma unroll
      for (int q = 0; q < 4; ++q) {
        float4 w = w4[q];
        acc[4 * q + 0] += xv * w.x; acc[4 * q + 1] += xv * w.y;
        acc[4 * q + 2] += xv * w.z; acc[4 * q + 3] += xv * w.w;
      }
    }
#pragma unroll
    for (int q = 0; q < 4; ++q)
      y4[cg * 4 + q] = make_float4(lrelu(acc[4 * q + 0], 0.01f), lrelu(acc[4 * q + 1], 0.01f),
                                   lrelu(acc[4 * q + 2], 0.01f), lrelu(acc[4 * q + 3], 0.01f));
  }
}

// H[N,64] = X[N,64] @ W; S1=H.a1; optional S2. X and H MAY ALIAS (row-private:
// each thread loads its whole row to registers before writing it back).
__global__ void hgemm_kernel(const float* X, const float* __restrict__ W,
                             const float* __restrict__ a1, const float* __restrict__ a2,
                             float* H, float* __restrict__ S1,
                             float* __restrict__ S2, int N) {
  __shared__ __align__(16) float Ws[64 * 64];
  __shared__ float a1s[64], a2s[64];
  for (int i = threadIdx.x; i < 64 * 64; i += blockDim.x) Ws[i] = W[i];
  if (threadIdx.x < 64) {
    a1s[threadIdx.x] = a1[threadIdx.x];
    a2s[threadIdx.x] = a2 ? a2[threadIdx.x] : 0.0f;
  }
  __syncthreads();
  int row = blockIdx.x * blockDim.x + threadIdx.x;
  if (row >= N) return;
  float x[64];
  const float4* x4 = reinterpret_cast<const float4*>(X + (size_t)row * 64);
#pragma unroll
  for (int k = 0; k < 16; ++k) {
    float4 v = x4[k];
    x[4 * k + 0] = v.x; x[4 * k + 1] = v.y; x[4 * k + 2] = v.z; x[4 * k + 3] = v.w;
  }
  float4* h4 = reinterpret_cast<float4*>(H + (size_t)row * 64);
  float s1 = 0.0f, s2 = 0.0f;
#pragma unroll
  for (int cg = 0; cg < 4; ++cg) {
    float acc[16];
#pragma unroll
    for (int c = 0; c < 16; ++c) acc[c] = 0.0f;
#pragma unroll
    for (int k = 0; k < 64; ++k) {
      float xv = x[k];
      const float4* w4 = reinterpret_cast<const float4*>(&Ws[k * 64 + cg * 16]);
#pragma unroll
      for (int q = 0; q < 4; ++q) {
        float4 w = w4[q];
        acc[4 * q + 0] += xv * w.x; acc[4 * q + 1] += xv * w.y;
        acc[4 * q + 2] += xv * w.z; acc[4 * q + 3] += xv * w.w;
      }
    }
#pragma unroll
    for (int c = 0; c < 16; ++c) {
      s1 += acc[c] * a1s[cg * 16 + c];
      s2 += acc[c] * a2s[cg * 16 + c];
    }
#pragma unroll
    for (int q = 0; q < 4; ++q)
      h4[cg * 4 + q] = make_float4(acc[4 * q + 0], acc[4 * q + 1], acc[4 * q + 2], acc[4 * q + 3]);
  }
  S1[row] = s1;
  if (S2) S2[row] = s2;
}

__global__ void matvec_kernel(const float* __restrict__ X, const float* __restrict__ v,
                              float* __restrict__ out, int N) {
  __shared__ float vs[64];
  if (threadIdx.x < 64) vs[threadIdx.x] = v[threadIdx.x];
  __syncthreads();
  int i = blockIdx.x * blockDim.x + threadIdx.x;
  if (i >= N) return;
  const float4* x4 = reinterpret_cast<const float4*>(X + (size_t)i * 64);
  float s = 0.0f;
#pragma unroll
  for (int k = 0; k < 16; ++k) {
    float4 u = x4[k];
    s += u.x * vs[4 * k + 0] + u.y * vs[4 * k + 1] + u.z * vs[4 * k + 2] + u.w * vs[4 * k + 3];
  }
  out[i] = s;
}

__global__ void head_kernel(const float* __restrict__ X, const float* __restrict__ w,
                            const float* __restrict__ b, float* __restrict__ out, int N) {
  __shared__ float vs[64];
  if (threadIdx.x < 64) vs[threadIdx.x] = w[threadIdx.x];
  __syncthreads();
  int i = blockIdx.x * blockDim.x + threadIdx.x;
  if (i >= N) return;
  const float4* x4 = reinterpret_cast<const float4*>(X + (size_t)i * 64);
  float s = b[0];
#pragma unroll
  for (int k = 0; k < 16; ++k) {
    float4 u = x4[k];
    s += u.x * vs[4 * k + 0] + u.y * vs[4 * k + 1] + u.z * vs[4 * k + 2] + u.w * vs[4 * k + 3];
  }
  out[i] = s;
}

__global__ void rowdot64_kernel(const float* __restrict__ M, const float* __restrict__ v,
                                float* __restrict__ out) {
  __shared__ float vs[64];
  vs[threadIdx.x] = v[threadIdx.x];
  __syncthreads();
  float s = 0.0f;
#pragma unroll
  for (int j = 0; j < 64; ++j) s += M[threadIdx.x * 64 + j] * vs[j];
  out[threadIdx.x] = s;
}

__global__ void edge_dots_kernel(const float* __restrict__ EA, const float* __restrict__ We,
                                 const float* __restrict__ be, const float* __restrict__ wa1,
                                 const float* __restrict__ wa2, float* __restrict__ hd1,
                                 float* __restrict__ hd2, int E) {
  __shared__ __align__(16) float Ws[16 * 64];
  __shared__ float bs[64], w1s[64], w2s[64];
  for (int i = threadIdx.x; i < 16 * 64; i += blockDim.x) Ws[i] = We[i];
  if (threadIdx.x < 64) {
    bs[threadIdx.x] = be[threadIdx.x];
    w1s[threadIdx.x] = wa1[threadIdx.x];
    w2s[threadIdx.x] = wa2 ? wa2[threadIdx.x] : 0.0f;
  }
  __syncthreads();
  int e = blockIdx.x * blockDim.x + threadIdx.x;
  if (e >= E) return;
  float x[16];
  const float4* x4 = reinterpret_cast<const float4*>(EA + (size_t)e * 16);
#pragma unroll
  for (int k = 0; k < 4; ++k) {
    float4 v = x4[k];
    x[4 * k + 0] = v.x; x[4 * k + 1] = v.y; x[4 * k + 2] = v.z; x[4 * k + 3] = v.w;
  }
  float d1 = 0.0f, d2 = 0.0f;
#pragma unroll
  for (int jg = 0; jg < 16; ++jg) {
    float4 t = *reinterpret_cast<const float4*>(&bs[jg * 4]);
#pragma unroll
    for (int k = 0; k < 16; ++k) {
      float4 w = *reinterpret_cast<const float4*>(&Ws[k * 64 + jg * 4]);
      t.x += x[k] * w.x; t.y += x[k] * w.y; t.z += x[k] * w.z; t.w += x[k] * w.w;
    }
    t.x = lrelu(t.x, 0.01f); t.y = lrelu(t.y, 0.01f);
    t.z = lrelu(t.z, 0.01f); t.w = lrelu(t.w, 0.01f);
    float4 w1 = *reinterpret_cast<const float4*>(&w1s[jg * 4]);
    float4 w2 = *reinterpret_cast<const float4*>(&w2s[jg * 4]);
    d1 += t.x * w1.x + t.y * w1.y + t.z * w1.z + t.w * w1.w;
    d2 += t.x * w2.x + t.y * w2.y + t.z * w2.z + t.w * w2.w;
  }
  hd1[e] = d1;
  if (hd2) hd2[e] = d2;
}

__global__ void edge_mean_kernel(const float* __restrict__ EA, const float* __restrict__ We,
                                 const float* __restrict__ be, float* __restrict__ sum_out, int E) {
  __shared__ float Ws[16 * 64];
  __shared__ float bs[64];
  __shared__ float eas[64 * 16];
  __shared__ float partial[256];
  for (int i = threadIdx.x; i < 16 * 64; i += blockDim.x) Ws[i] = We[i];
  if (threadIdx.x < 64) bs[threadIdx.x] = be[threadIdx.x];
  int j = threadIdx.x & 63, q = threadIdx.x >> 6;
  float acc = 0.0f;
  for (int base = blockIdx.x * 64; base < E; base += gridDim.x * 64) {
    int tile = min(64, E - base);
    __syncthreads();
    for (int i = threadIdx.x; i < tile * 16; i += blockDim.x) eas[i] = EA[(size_t)base * 16 + i];
    __syncthreads();
    for (int e = q; e < tile; e += 4) {
      float t = bs[j];
#pragma unroll
      for (int k = 0; k < 16; ++k) t += eas[e * 16 + k] * Ws[k * 64 + j];
      acc += lrelu(t, 0.01f);
    }
  }
  partial[threadIdx.x] = acc;
  __syncthreads();
  if (q == 0) {
    float s = partial[j] + partial[64 + j] + partial[128 + j] + partial[192 + j];
    atomicAdd(&sum_out[j], s);
  }
}

__global__ void selfdot_kernel(const float* __restrict__ sum, const float* __restrict__ wa,
                               float invE, float* __restrict__ out) {
  float v = sum[threadIdx.x] * wa[threadIdx.x] * invE;
#pragma unroll
  for (int o = 32; o >= 1; o >>= 1) v += __shfl_down(v, o, 64);
  if (threadIdx.x == 0) out[0] = v;
}

__global__ void biasinit_kernel(float* __restrict__ out, const float* __restrict__ b1,
                                const float* __restrict__ b2, int N) {
  __shared__ float bs[64];
  if (threadIdx.x < 64)
    bs[threadIdx.x] = b1[threadIdx.x] + (b2 ? b2[threadIdx.x] : 0.0f);
  __syncthreads();
  size_t total = (size_t)N * 64;
  for (size_t t = (size_t)blockIdx.x * blockDim.x + threadIdx.x; t < total;
       t += (size_t)gridDim.x * blockDim.x)
    out[t] = bs[t & 63];
}

__global__ void attw_kernel(const int* __restrict__ src, const int* __restrict__ dst,
                            const float* __restrict__ ssrc, const float* __restrict__ sdst,
                            const float* __restrict__ hd, const float* __restrict__ selfhd,
                            float* __restrict__ wbuf, float* __restrict__ denom,
                            int E, int Nloop) {
  int e = blockIdx.x * blockDim.x + threadIdx.x;
  int total = E + Nloop;
  if (e >= total) return;
  int s, d;
  float h;
  if (e < E) { s = src[e]; d = dst[e]; h = hd[e]; }
  else       { s = e - E;  d = s;      h = selfhd[0]; }
  float w = __expf(lrelu(ssrc[s] + sdst[d] + h, 0.2f));
  wbuf[e] = w;
  atomicAdd(&denom[d], w);
}

__global__ void attnorm_kernel(const int* __restrict__ dst, const float* __restrict__ denom,
                               float* __restrict__ wbuf, int E, int Nloop) {
  int e = blockIdx.x * blockDim.x + threadIdx.x;
  int total = E + Nloop;
  if (e >= total) return;
  int d = (e < E) ? dst[e] : (e - E);
  wbuf[e] = wbuf[e] / (denom[d] + 1e-16f);
}

__global__ void aggregate_kernel(const int* __restrict__ src, const int* __restrict__ dst,
                                 const float* __restrict__ alpha,
                                 const float* __restrict__ H, float* __restrict__ out,
                                 int E, int Nloop) {
  size_t total = (size_t)(E + Nloop) * 64;
  for (size_t t = (size_t)blockIdx.x * blockDim.x + threadIdx.x; t < total;
       t += (size_t)gridDim.x * blockDim.x) {
    int e = (int)(t >> 6);
    int c = (int)(t & 63);
    int s, d;
    if (e < E) { s = src[e]; d = dst[e]; }
    else       { s = e - E;  d = s; }
    atomicAdd(&out[(size_t)d * 64 + c], H[(size_t)s * 64 + c] * alpha[e]);
  }
}

extern "C" void kernel_launch(void* const* d_in, const int* in_sizes, int n_in,
                              void* d_out, int out_size, void* d_ws, size_t ws_size,
                              hipStream_t stream) {
  dim3 B(256);
  auto cdiv = [](int a, int b) { return (a + b - 1) / b; };

  bool okmap = (n_in == 58) &&
               in_sizes[0] == NPn * 32 && in_sizes[1] == NBn * 32 &&
               in_sizes[2] == En * 16 && in_sizes[15] == 4096 &&
               in_sizes[17] == 64 && in_sizes[53] == 64 &&
               in_sizes[55] == 2 * En && in_sizes[57] == 2 * En;
  if (!okmap) {
    fill_kernel<<<cdiv(NPn, 256), B, 0, stream>>>((float*)d_out, 1000.0f, NPn);
    return;
  }

  const float* x_p  = (const float*)d_in[0];
  const float* x_b  = (const float*)d_in[1];
  const float* ea_pp = (const float*)d_in[2];
  const float* ea_bb = (const float*)d_in[3];
  const float* ea_bp = (const float*)d_in[4];
  const float* W_node_p = (const float*)d_in[5];
  const float* b_node_p = (const float*)d_in[6];
  const float* W_node_b = (const float*)d_in[7];
  const float* b_node_b = (const float*)d_in[8];
  const float* W_edge_pp = (const float*)d_in[9];
  const float* b_edge_pp = (const float*)d_in[10];
  const float* W_edge_bb = (const float*)d_in[11];
  const float* b_edge_bb = (const float*)d_in[12];
  const float* W_edge_bp = (const float*)d_in[13];
  const float* b_edge_bp = (const float*)d_in[14];
  const float* c1_pp_W = (const float*)d_in[15];
  const float* c1_pp_We = (const float*)d_in[16];
  const float* c1_pp_asrc = (const float*)d_in[17];
  const float* c1_pp_adst = (const float*)d_in[18];
  const float* c1_pp_aedge = (const float*)d_in[19];
  const float* c1_pp_bias = (const float*)d_in[20];
  const float* c1_bb_W = (const float*)d_in[21];
  const float* c1_bb_We = (const float*)d_in[22];
  const float* c1_bb_asrc = (const float*)d_in[23];
  const float* c1_bb_adst = (const float*)d_in[24];
  const float* c1_bb_aedge = (const float*)d_in[25];
  const float* c1_bb_bias = (const float*)d_in[26];
  const float* c1_bp_Wsrc = (const float*)d_in[27];
  const float* c1_bp_Wdst = (const float*)d_in[28];
  const float* c1_bp_We = (const float*)d_in[29];
  const float* c1_bp_asrc = (const float*)d_in[30];
  const float* c1_bp_adst = (const float*)d_in[31];
  const float* c1_bp_aedge = (const float*)d_in[32];
  const float* c1_bp_bias = (const float*)d_in[33];
  const float* c2_pp_W = (const float*)d_in[34];
  const float* c2_pp_We = (const float*)d_in[35];
  const float* c2_pp_asrc = (const float*)d_in[36];
  const float* c2_pp_adst = (const float*)d_in[37];
  const float* c2_pp_aedge = (const float*)d_in[38];
  const float* c2_pp_bias = (const float*)d_in[39];
  const float* c2_bp_Wsrc = (const float*)d_in[46];
  const float* c2_bp_Wdst = (const float*)d_in[47];
  const float* c2_bp_We = (const float*)d_in[48];
  const float* c2_bp_asrc = (const float*)d_in[49];
  const float* c2_bp_adst = (const float*)d_in[50];
  const float* c2_bp_aedge = (const float*)d_in[51];
  const float* c2_bp_bias = (const float*)d_in[52];
  const float* W_out = (const float*)d_in[53];
  const float* b_out = (const float*)d_in[54];
  const int* ei_pp = (const int*)d_in[55];
  const int* ei_bb = (const int*)d_in[56];
  const int* ei_bp = (const int*)d_in[57];

  float* ws   = (float*)d_ws;
  unsigned* diag = (unsigned*)ws;             // [32]
  float* res  = ws + 32;                      // [NPn]
  float* xp   = res + NPn;                    // [NPn*64]  (p2 aliases)
  float* p1   = xp + (size_t)NPn * 64;        // [NPn*64]
  float* b1v  = p1 + (size_t)NPn * 64;        // [NBn*64]
  float* hbuf = b1v + (size_t)NBn * 64;       // [NBn*64]
  float* hd_pp1 = hbuf + (size_t)NBn * 64;    // [En] x5
  float* hd_pp2 = hd_pp1 + En;
  float* hd_bb1 = hd_pp2 + En;
  float* hd_bp1 = hd_bb1 + En;
  float* hd_bp2 = hd_bp1 + En;
  float* wbuf = hd_bp2 + En;                  // [En+NBn]
  float* s_src = wbuf + (En + NBn);           // [NBn]
  float* s_dst = s_src + NBn;                 // [NBn]
  float* denom = s_dst + NBn;                 // [NBn]
  float* small = denom + NBn;                 // [1024]
  float* p2   = xp;

  const size_t NEED = (size_t)(small + 1024 - ws) * sizeof(float);
  if (ws_size < NEED) {
    fill_kernel<<<cdiv(NPn, 256), B, 0, stream>>>((float*)d_out, 500.0f, NPn);
    return;
  }

  float* sum_pp  = small + 0;   float* sum_bb  = small + 64;
  float* wa_pp1  = small + 128; float* wa_pp2  = small + 192;
  float* wa_bb1  = small + 256; float* wa_bp1  = small + 320; float* wa_bp2 = small + 384;
  float* wd1     = small + 448; float* wd2     = small + 512;
  float* self_pp1= small + 576; float* self_pp2= small + 577; float* self_bb1 = small + 578;
  const float invE = 1.0f / (float)En;

  hipMemsetAsync(diag, 0, 32 * sizeof(unsigned), stream);
  hipMemsetAsync(sum_pp, 0, 128 * sizeof(float), stream);

  // slot 0: raw inputs; slot 1: weights
  scan_kernel<<<2048, B, 0, stream>>>(x_p, (size_t)NPn * 32, diag, 0);
  scan_kernel<<<2048, B, 0, stream>>>(x_b, (size_t)NBn * 32, diag, 0);
  scan_kernel<<<2048, B, 0, stream>>>(ea_pp, (size_t)En * 16, diag, 0);
  scan_kernel<<<2048, B, 0, stream>>>(ea_bb, (size_t)En * 16, diag, 0);
  scan_kernel<<<2048, B, 0, stream>>>(ea_bp, (size_t)En * 16, diag, 0);
  WP wp;
  {
    static const int idx[44] = {5,6,7,8,9,10,11,12,13,14,
                                15,16,17,18,19,20, 21,22,23,24,25,26,
                                27,28,29,30,31,32,33, 34,35,36,37,38,39,
                                46,47,48,49,50,51,52, 53,54};
    for (int i = 0; i < 44; ++i) wp.p[i] = d_in[idx[i]];
  }
  scan_weights_kernel<<<44, B, 0, stream>>>(wp, diag, 1);

  // p-projection -> slot 2
  proj_kernel<<<cdiv(NPn, 256), B, 0, stream>>>(x_p, W_node_p, b_node_p, xp, NPn);
  scan_kernel<<<2048, B, 0, stream>>>(xp, (size_t)NPn * 64, diag, 2);

  rowdot64_kernel<<<1, 64, 0, stream>>>(c1_pp_We, c1_pp_aedge, wa_pp1);
  rowdot64_kernel<<<1, 64, 0, stream>>>(c2_pp_We, c2_pp_aedge, wa_pp2);
  rowdot64_kernel<<<1, 64, 0, stream>>>(c1_bb_We, c1_bb_aedge, wa_bb1);
  rowdot64_kernel<<<1, 64, 0, stream>>>(c1_bp_We, c1_bp_aedge, wa_bp1);
  rowdot64_kernel<<<1, 64, 0, stream>>>(c2_bp_We, c2_bp_aedge, wa_bp2);
  rowdot64_kernel<<<1, 64, 0, stream>>>(c1_bp_Wdst, c1_bp_adst, wd1);
  rowdot64_kernel<<<1, 64, 0, stream>>>(c2_bp_Wdst, c2_bp_adst, wd2);

  // edge scalars -> slot 3 ; small -> slot 4
  edge_dots_kernel<<<cdiv(En, 256), B, 0, stream>>>(ea_pp, W_edge_pp, b_edge_pp, wa_pp1, wa_pp2, hd_pp1, hd_pp2, En);
  edge_dots_kernel<<<cdiv(En, 256), B, 0, stream>>>(ea_bb, W_edge_bb, b_edge_bb, wa_bb1, nullptr, hd_bb1, nullptr, En);
  edge_dots_kernel<<<cdiv(En, 256), B, 0, stream>>>(ea_bp, W_edge_bp, b_edge_bp, wa_bp1, wa_bp2, hd_bp1, hd_bp2, En);
  scan_kernel<<<2048, B, 0, stream>>>(hd_pp1, (size_t)En * 5, diag, 3);

  edge_mean_kernel<<<512, B, 0, stream>>>(ea_pp, W_edge_pp, b_edge_pp, sum_pp, En);
  edge_mean_kernel<<<512, B, 0, stream>>>(ea_bb, W_edge_bb, b_edge_bb, sum_bb, En);
  selfdot_kernel<<<1, 64, 0, stream>>>(sum_pp, wa_pp1, invE, self_pp1);
  selfdot_kernel<<<1, 64, 0, stream>>>(sum_pp, wa_pp2, invE, self_pp2);
  selfdot_kernel<<<1, 64, 0, stream>>>(sum_bb, wa_bb1, invE, self_bb1);
  scan_kernel<<<4, B, 0, stream>>>(small, 640, diag, 4);

  // ---- conv1 pp: slots 5 (h,s), 6 (wbuf,denom), 7 (p1)
  hgemm_kernel<<<cdiv(NPn, 256), B, 0, stream>>>(xp, c1_pp_W, c1_pp_asrc, c1_pp_adst, hbuf, s_src, s_dst, NPn);
  scan_kernel<<<2048, B, 0, stream>>>(hbuf, (size_t)NPn * 64, diag, 5);
  scan_kernel<<<256, B, 0, stream>>>(s_src, NPn, diag, 5);
  scan_kernel<<<256, B, 0, stream>>>(s_dst, NPn, diag, 5);
  hipMemsetAsync(denom, 0, (size_t)NPn * 4, stream);
  biasinit_kernel<<<1024, B, 0, stream>>>(p1, c1_pp_bias, c1_bp_bias, NPn);
  attw_kernel<<<cdiv(En + NPn, 256), B, 0, stream>>>(ei_pp, ei_pp + En, s_src, s_dst, hd_pp1, self_pp1, wbuf, denom, En, NPn);
  scan_kernel<<<1024, B, 0, stream>>>(wbuf, (size_t)(En + NPn), diag, 6);
  scan_kernel<<<256, B, 0, stream>>>(denom, NPn, diag, 6);
  attnorm_kernel<<<cdiv(En + NPn, 256), B, 0, stream>>>(ei_pp + En, denom, wbuf, En, NPn);
  aggregate_kernel<<<8192, B, 0, stream>>>(ei_pp, ei_pp + En, wbuf, hbuf, p1, En, NPn);
  scan_kernel<<<2048, B, 0, stream>>>(p1, (size_t)NPn * 64, diag, 7);

  // ---- conv1 bp: slots 8 (b-proj), 9 (gemm h + s_src), 10 (s_dst), 11 (wbuf,denom), 12 (p1)
  proj_kernel<<<cdiv(NBn, 256), B, 0, stream>>>(x_b, W_node_b, b_node_b, hbuf, NBn);
  scan_kernel<<<2048, B, 0, stream>>>(hbuf, (size_t)NBn * 64, diag, 8);
  hgemm_kernel<<<cdiv(NBn, 256), B, 0, stream>>>(hbuf, c1_bp_Wsrc, c1_bp_asrc, nullptr, hbuf, s_src, nullptr, NBn);  // in-place, row-private
  scan_kernel<<<2048, B, 0, stream>>>(hbuf, (size_t)NBn * 64, diag, 9);
  scan_kernel<<<256, B, 0, stream>>>(s_src, NBn, diag, 9);
  matvec_kernel<<<cdiv(NPn, 256), B, 0, stream>>>(xp, wd1, s_dst, NPn);
  scan_kernel<<<256, B, 0, stream>>>(s_dst, NPn, diag, 10);
  hipMemsetAsync(denom, 0, (size_t)NPn * 4, stream);
  attw_kernel<<<cdiv(En, 256), B, 0, stream>>>(ei_bp, ei_bp + En, s_src, s_dst, hd_bp1, nullptr, wbuf, denom, En, 0);
  scan_kernel<<<1024, B, 0, stream>>>(wbuf, (size_t)En, diag, 11);
  scan_kernel<<<256, B, 0, stream>>>(denom, NPn, diag, 11);
  attnorm_kernel<<<cdiv(En, 256), B, 0, stream>>>(ei_bp + En, denom, wbuf, En, 0);
  aggregate_kernel<<<8192, B, 0, stream>>>(ei_bp, ei_bp + En, wbuf, hbuf, p1, En, 0);
  scan_kernel<<<2048, B, 0, stream>>>(p1, (size_t)NPn * 64, diag, 12);

  // ---- conv1 bb: slots 13 (proj), 14 (h,s), 15 (wbuf,denom), 16 (b1v)
  proj_kernel<<<cdiv(NBn, 256), B, 0, stream>>>(x_b, W_node_b, b_node_b, hbuf, NBn);
  scan_kernel<<<2048, B, 0, stream>>>(hbuf, (size_t)NBn * 64, diag, 13);
  hgemm_kernel<<<cdiv(NBn, 256), B, 0, stream>>>(hbuf, c1_bb_W, c1_bb_asrc, c1_bb_adst, hbuf, s_src, s_dst, NBn);  // in-place
  scan_kernel<<<2048, B, 0, stream>>>(hbuf, (size_t)NBn * 64, diag, 14);
  scan_kernel<<<256, B, 0, stream>>>(s_src, NBn, diag, 14);
  scan_kernel<<<256, B, 0, stream>>>(s_dst, NBn, diag, 14);
  hipMemsetAsync(denom, 0, (size_t)NBn * 4, stream);
  biasinit_kernel<<<1024, B, 0, stream>>>(b1v, c1_bb_bias, nullptr, NBn);
  attw_kernel<<<cdiv(En + NBn, 256), B, 0, stream>>>(ei_bb, ei_bb + En, s_src, s_dst, hd_bb1, self_bb1, wbuf, denom, En, NBn);
  scan_kernel<<<1024, B, 0, stream>>>(wbuf, (size_t)(En + NBn), diag, 15);
  scan_kernel<<<256, B, 0, stream>>>(denom, NBn, diag, 15);
  attnorm_kernel<<<cdiv(En + NBn, 256), B, 0, stream>>>(ei_bb + En, denom, wbuf, En, NBn);
  aggregate_kernel<<<8192, B, 0, stream>>>(ei_bb, ei_bb + En, wbuf, hbuf, b1v, En, NBn);
  scan_kernel<<<2048, B, 0, stream>>>(b1v, (size_t)NBn * 64, diag, 16);

  // ---- conv2 pp: slots 17 (h), 18 (wbuf,denom), 19 (p2)
  hgemm_kernel<<<cdiv(NPn, 256), B, 0, stream>>>(p1, c2_pp_W, c2_pp_asrc, c2_pp_adst, hbuf, s_src, s_dst, NPn);
  scan_kernel<<<2048, B, 0, stream>>>(hbuf, (size_t)NPn * 64, diag, 17);
  hipMemsetAsync(denom, 0, (size_t)NPn * 4, stream);
  biasinit_kernel<<<1024, B, 0, stream>>>(p2, c2_pp_bias, c2_bp_bias, NPn);
  attw_kernel<<<cdiv(En + NPn, 256), B, 0, stream>>>(ei_pp, ei_pp + En, s_src, s_dst, hd_pp2, self_pp2, wbuf, denom, En, NPn);
  scan_kernel<<<1024, B, 0, stream>>>(wbuf, (size_t)(En + NPn), diag, 18);
  scan_kernel<<<256, B, 0, stream>>>(denom, NPn, diag, 18);
  attnorm_kernel<<<cdiv(En + NPn, 256), B, 0, stream>>>(ei_pp + En, denom, wbuf, En, NPn);
  aggregate_kernel<<<8192, B, 0, stream>>>(ei_pp, ei_pp + En, wbuf, hbuf, p2, En, NPn);
  scan_kernel<<<2048, B, 0, stream>>>(p2, (size_t)NPn * 64, diag, 19);

  // ---- conv2 bp: slots 20 (h,s), 21 (wbuf,denom), 22 (p2, res)
  hgemm_kernel<<<cdiv(NBn, 256), B, 0, stream>>>(b1v, c2_bp_Wsrc, c2_bp_asrc, nullptr, hbuf, s_src, nullptr, NBn);
  matvec_kernel<<<cdiv(NPn, 256), B, 0, stream>>>(p1, wd2, s_dst, NPn);
  scan_kernel<<<2048, B, 0, stream>>>(hbuf, (size_t)NBn * 64, diag, 20);
  scan_kernel<<<256, B, 0, stream>>>(s_src, NBn, diag, 20);
  scan_kernel<<<256, B, 0, stream>>>(s_dst, NPn, diag, 20);
  hipMemsetAsync(denom, 0, (size_t)NPn * 4, stream);
  attw_kernel<<<cdiv(En, 256), B, 0, stream>>>(ei_bp, ei_bp + En, s_src, s_dst, hd_bp2, nullptr, wbuf, denom, En, 0);
  scan_kernel<<<1024, B, 0, stream>>>(wbuf, (size_t)En, diag, 21);
  scan_kernel<<<256, B, 0, stream>>>(denom, NPn, diag, 21);
  attnorm_kernel<<<cdiv(En, 256), B, 0, stream>>>(ei_bp + En, denom, wbuf, En, 0);
  aggregate_kernel<<<8192, B, 0, stream>>>(ei_bp, ei_bp + En, wbuf, hbuf, p2, En, 0);
  scan_kernel<<<2048, B, 0, stream>>>(p2, (size_t)NPn * 64, diag, 22);

  head_kernel<<<cdiv(NPn, 256), B, 0, stream>>>(p2, W_out, b_out, res, NPn);
  scan_kernel<<<256, B, 0, stream>>>(res, NPn, diag, 22);
  encode_kernel<<<cdiv(NPn, 256), B, 0, stream>>>(diag, res, (float*)d_out, NPn);
}